// Round 1
// baseline (89992.401 us; speedup 1.0000x reference)
//
#include <hip/hip_runtime.h>
#include <math.h>

// Problem constants
constexpr int H   = 256;
constexpr int B   = 64;
constexpr int T   = 2048;
constexpr int G   = 64;    // blocks
constexpr int NTH = 512;   // threads per block (8 waves)
constexpr int HB  = H * B; // 16384

struct SharedMain {
    float wU[256][16];   // W_ih slice, [k][cl], cl = gate*4+oi
    float wV[256][16];   // W_hh slice
    float wA[768][4];    // W_e (rows 0..511) + W_b (rows 512..767), [r][i]
    float U[64][17];     // x@W_ih^T partial results (padded vs bank conflicts)
    float V[64][17];     // h@W_hh^T
    float ap[64][5];     // 'a' partials (pre-tanh), padded
    alignas(16) float outst[64][4];  // output staging for float4 store
    float jp[8][64];     // per-wave j partial sums
    float bg[16];        // b_ih+b_hh slice
    float ba[4];         // b_e+b_b slice
    float v4[4];         // v_b slice
    float s[64];         // softmax weights
};
union SharedAll {
    SharedMain m;
    float tile[64][65];  // transpose staging (aliases weight region; used first)
};

__device__ __forceinline__ float sigmoidf_(float v) {
    return 1.0f / (1.0f + expf(-v));
}

// Monotonic-epoch grid barrier. Requires cooperative launch (co-residency).
__device__ __forceinline__ void grid_barrier(unsigned* bar, unsigned target) {
    __syncthreads();
    if (threadIdx.x == 0) {
        __threadfence();  // release: flush our writes to device scope
        __hip_atomic_fetch_add(bar, 1u, __ATOMIC_ACQ_REL, __HIP_MEMORY_SCOPE_AGENT);
        while (__hip_atomic_load(bar, __ATOMIC_ACQUIRE, __HIP_MEMORY_SCOPE_AGENT) < target) {
            __builtin_amdgcn_s_sleep(1);
        }
        __threadfence();  // acquire: invalidate caches so the block sees fresh data
    }
    __syncthreads();
}

__global__ void __launch_bounds__(NTH, 1)
scan_kernel(const float* __restrict__ x,
            const float* __restrict__ W_b,  const float* __restrict__ b_b,
            const float* __restrict__ v_b,  const float* __restrict__ W_e,
            const float* __restrict__ b_e,  const float* __restrict__ W_ih,
            const float* __restrict__ W_hh, const float* __restrict__ b_ih,
            const float* __restrict__ b_hh,
            float* __restrict__ out, float* __restrict__ wsf,
            unsigned* __restrict__ bar)
{
    __shared__ SharedAll sh;
    const int tid = threadIdx.x;
    const int g   = blockIdx.x;

    float* pJ = wsf + 64;        // [G][64] j partials, 256B offset from bar
    float* hT = pJ + G * 64;     // [H][B] transposed h state
    float* cT = hT + HB;         // [H][B] transposed c state
    float* xT = out;             // reuse output buffer: xT[t] dead before out[t] written

    // ---------- Phase 0: transpose x[t][b][k] -> xT[t][k][b] ----------
    for (int tl = g; tl < T * 4; tl += G) {
        const int t  = tl >> 2;
        const int kc = (tl & 3) << 6;
        __syncthreads();
        for (int q = tid; q < 1024; q += NTH) {
            const int r  = q >> 4;
            const int c4 = (q & 15) << 2;
            const float4 v = *(const float4*)(x + (size_t)t * HB + (size_t)r * H + kc + c4);
            sh.tile[r][c4 + 0] = v.x; sh.tile[r][c4 + 1] = v.y;
            sh.tile[r][c4 + 2] = v.z; sh.tile[r][c4 + 3] = v.w;
        }
        __syncthreads();
        for (int q = tid; q < 1024; q += NTH) {
            const int k  = q >> 4;
            const int b4 = (q & 15) << 2;
            float4 v;
            v.x = sh.tile[b4 + 0][k]; v.y = sh.tile[b4 + 1][k];
            v.z = sh.tile[b4 + 2][k]; v.w = sh.tile[b4 + 3][k];
            *(float4*)(xT + (size_t)t * HB + (size_t)(kc + k) * B + b4) = v;
        }
    }
    __syncthreads();

    // ---------- Phase 1: weights -> LDS (block owns h-cols 4g..4g+3) ----------
    for (int e = tid; e < 256 * 16; e += NTH) {
        const int k  = e >> 4;
        const int cl = e & 15;
        const int gate = cl >> 2, oi = cl & 3;
        const int row = gate * H + 4 * g + oi;
        sh.m.wU[k][cl] = W_ih[(size_t)row * H + k];
        sh.m.wV[k][cl] = W_hh[(size_t)row * H + k];
    }
    for (int e = tid; e < 768 * 4; e += NTH) {
        const int r = e >> 2;
        const int i = e & 3;
        const int col = 4 * g + i;
        float w;
        if (r < 512) w = W_e[(size_t)col * 512 + r];
        else         w = W_b[(size_t)col * 256 + (r - 512)];
        sh.m.wA[r][i] = w;
    }
    if (tid < 16) {
        const int gate = tid >> 2, oi = tid & 3;
        const int col = gate * H + 4 * g + oi;
        sh.m.bg[tid] = b_ih[col] + b_hh[col];
    }
    if (tid < 4) {
        sh.m.ba[tid] = b_e[4 * g + tid] + b_b[4 * g + tid];
        sh.m.v4[tid] = v_b[4 * g + tid];
    }
    // zero h,c (hT and cT are contiguous: 32768 floats == G*NTH)
    hT[g * NTH + tid] = 0.0f;

    unsigned nb = 0;
    ++nb; grid_barrier(bar, nb * (unsigned)G);

    const int wv = tid >> 6;   // wave 0..7
    const int b  = tid & 63;   // lane = batch index

    // ---------- Main scan ----------
    for (int t = 0; t < T; ++t) {
        // zero accumulators
        for (int e = tid; e < 64 * 17; e += NTH) { (&sh.m.U[0][0])[e] = 0.0f; (&sh.m.V[0][0])[e] = 0.0f; }
        for (int e = tid; e < 64 * 5; e += NTH) (&sh.m.ap[0][0])[e] = 0.0f;
        __syncthreads();

        if (wv < 4) {
            // U = x_t @ W_ih^T slice  (+ A x-part), k-quarter wv
            const int krow = wv << 6;
            const float* src = xT + (size_t)t * HB + (size_t)krow * B;
            float aU[16], aA[4];
            #pragma unroll
            for (int c = 0; c < 16; ++c) aU[c] = 0.0f;
            aA[0] = aA[1] = aA[2] = aA[3] = 0.0f;
            #pragma unroll 4
            for (int kk = 0; kk < 64; ++kk) {
                const float xv = src[kk * B + b];
                const float* wr = sh.m.wU[krow + kk];
                #pragma unroll
                for (int c = 0; c < 16; ++c) aU[c] = fmaf(xv, wr[c], aU[c]);
                const float* wa = sh.m.wA[512 + krow + kk];
                #pragma unroll
                for (int i = 0; i < 4; ++i) aA[i] = fmaf(xv, wa[i], aA[i]);
            }
            #pragma unroll
            for (int c = 0; c < 16; ++c) atomicAdd(&sh.m.U[b][c], aU[c]);
            #pragma unroll
            for (int i = 0; i < 4; ++i) atomicAdd(&sh.m.ap[b][i], aA[i]);
        } else {
            // V = h @ W_hh^T slice  (+ A h-part + A c-part), k-quarter wv-4
            const int krow = (wv - 4) << 6;
            const float* sH = hT + (size_t)krow * B;
            const float* sC = cT + (size_t)krow * B;
            float aV[16], aA[4];
            #pragma unroll
            for (int c = 0; c < 16; ++c) aV[c] = 0.0f;
            aA[0] = aA[1] = aA[2] = aA[3] = 0.0f;
            #pragma unroll 4
            for (int kk = 0; kk < 64; ++kk) {
                const float hv = sH[kk * B + b];
                const float cv = sC[kk * B + b];
                const float* wr = sh.m.wV[krow + kk];
                #pragma unroll
                for (int c = 0; c < 16; ++c) aV[c] = fmaf(hv, wr[c], aV[c]);
                const float* waH = sh.m.wA[krow + kk];
                const float* waC = sh.m.wA[256 + krow + kk];
                #pragma unroll
                for (int i = 0; i < 4; ++i) aA[i] = fmaf(hv, waH[i], fmaf(cv, waC[i], aA[i]));
            }
            #pragma unroll
            for (int c = 0; c < 16; ++c) atomicAdd(&sh.m.V[b][c], aV[c]);
            #pragma unroll
            for (int i = 0; i < 4; ++i) atomicAdd(&sh.m.ap[b][i], aA[i]);
        }
        __syncthreads();

        // finish 'a': tanh, dot with v -> per-block j partial
        if (tid < 64) {
            float pj = 0.0f;
            #pragma unroll
            for (int i = 0; i < 4; ++i)
                pj += tanhf(sh.m.ap[tid][i] + sh.m.ba[i]) * sh.m.v4[i];
            pJ[g * 64 + tid] = pj;
        }
        ++nb; grid_barrier(bar, nb * (unsigned)G);

        // j reduction (all waves), then softmax over batch (wave 0)
        {
            float jpart = 0.0f;
            const int base = wv * 8;
            #pragma unroll
            for (int gg = 0; gg < 8; ++gg) jpart += pJ[(base + gg) * 64 + b];
            sh.m.jp[wv][b] = jpart;
        }
        __syncthreads();
        if (tid < 64) {
            float jv = 0.0f;
            #pragma unroll
            for (int w = 0; w < 8; ++w) jv += sh.m.jp[w][tid];
            float mx = jv;
            #pragma unroll
            for (int off = 32; off; off >>= 1) mx = fmaxf(mx, __shfl_xor(mx, off));
            const float e = expf(jv - mx);
            float ssum = e;
            #pragma unroll
            for (int off = 32; off; off >>= 1) ssum += __shfl_xor(ssum, off);
            sh.m.s[tid] = e / ssum;
        }
        __syncthreads();

        // gates + LSTM cell update for our 4 h-columns
        if (tid < 256) {
            const int oi = tid >> 6;
            const int bb = tid & 63;
            const float sb = sh.m.s[bb];
            const float pI = fmaf(sb, sh.m.U[bb][0  + oi], sh.m.V[bb][0  + oi]) + sh.m.bg[0  + oi];
            const float pF = fmaf(sb, sh.m.U[bb][4  + oi], sh.m.V[bb][4  + oi]) + sh.m.bg[4  + oi];
            const float pG = fmaf(sb, sh.m.U[bb][8  + oi], sh.m.V[bb][8  + oi]) + sh.m.bg[8  + oi];
            const float pO = fmaf(sb, sh.m.U[bb][12 + oi], sh.m.V[bb][12 + oi]) + sh.m.bg[12 + oi];
            const int col = 4 * g + oi;
            const float cold = cT[col * B + bb];
            const float cnew = sigmoidf_(pF) * cold + sigmoidf_(pI) * tanhf(pG);
            const float hnew = sigmoidf_(pO) * tanhf(cnew);
            cT[col * B + bb] = cnew;
            hT[col * B + bb] = hnew;
            sh.m.outst[bb][oi] = hnew;
        }
        __syncthreads();
        if (tid < 64) {
            const float4 v = *(const float4*)sh.m.outst[tid];
            *(float4*)(out + (size_t)t * HB + (size_t)tid * H + 4 * g) = v;
        }
        ++nb; grid_barrier(bar, nb * (unsigned)G);
    }
}

extern "C" void kernel_launch(void* const* d_in, const int* in_sizes, int n_in,
                              void* d_out, int out_size, void* d_ws, size_t ws_size,
                              hipStream_t stream) {
    const float* x    = (const float*)d_in[0];
    const float* W_b  = (const float*)d_in[1];
    const float* b_b  = (const float*)d_in[2];
    const float* v_b  = (const float*)d_in[3];
    const float* W_e  = (const float*)d_in[4];
    const float* b_e  = (const float*)d_in[5];
    const float* W_ih = (const float*)d_in[6];
    const float* W_hh = (const float*)d_in[7];
    const float* b_ih = (const float*)d_in[8];
    const float* b_hh = (const float*)d_in[9];
    float*    out = (float*)d_out;
    float*    wsf = (float*)d_ws;
    unsigned* bar = (unsigned*)d_ws;

    // zero the barrier counter (ws is poisoned before every launch)
    hipMemsetAsync(d_ws, 0, 256, stream);

    void* args[] = { &x, &W_b, &b_b, &v_b, &W_e, &b_e, &W_ih, &W_hh, &b_ih, &b_hh,
                     &out, &wsf, &bar };
    hipLaunchCooperativeKernel((void*)scan_kernel, dim3(G), dim3(NTH), args, 0, stream);
}